// Round 15
// baseline (1637.168 us; speedup 1.0000x reference)
//
#include <hip/hip_runtime.h>
#include <math.h>

// ---- problem dims ----
constexpr int BB = 16;      // batch
constexpr int SS = 1024;    // prefix len
constexpr int CC = 8;       // chunk len
constexpr int VV = 50257;   // vocab
constexpr int DD = 512;     // d_model
constexpr int EE = 8;       // experts
constexpr int HH = 512;     // expert hidden
constexpr int RR = 32;      // low rank
constexpr int FF = 1024;    // fused dim
constexpr int RTd = 512;    // target dim
constexpr int CDd = 64;     // code dim
constexpr int QQ = 128;     // query dim
constexpr int SCH = 128;    // s-chunk for AUG+scan

typedef short bf16x8 __attribute__((ext_vector_type(8)));
typedef float f32x4 __attribute__((ext_vector_type(4)));

__device__ __forceinline__ float sigm(float x){ return 1.0f/(1.0f+expf(-x)); }

__device__ __forceinline__ unsigned short f2bf(float f){
  unsigned int u = __float_as_uint(f);
  u += 0x7fff + ((u>>16)&1);
  return (unsigned short)(u>>16);
}
__device__ __forceinline__ float bf2f(unsigned short h){
  return __uint_as_float(((unsigned int)h)<<16);
}

// async global->LDS, 16B per lane; lds ptr wave-uniform, HW adds lane*16
__device__ __forceinline__ void gload16(unsigned short* l, const unsigned short* g){
  __builtin_amdgcn_global_load_lds(
      (const __attribute__((address_space(1))) unsigned int*)(g),
      (__attribute__((address_space(3))) unsigned int*)(l), 16, 0, 0);
}

// ---------------- gather_pack: emb[toks] -> packed bf16 hi/lo staging image ----------------
// xp layout: [b][c(8)][kc(16)][pb(1024)][8 shorts]; pb = row*8 + ((kq*2+h)^(row&7))
__global__ __launch_bounds__(256) void gather_pack(const int* __restrict__ toks,
    const float* __restrict__ emb, unsigned short* __restrict__ xp){
  int id = blockIdx.x*256 + threadIdx.x;        // 2,097,152 blocks
  int b = id >> 17;
  int rem = id & 131071;
  int c = rem >> 14;
  int rem2 = rem & 16383;
  int kc = rem2 >> 10;
  int pb = rem2 & 1023;
  int row = pb >> 3, q = pb & 7;
  int v = q ^ (row & 7);
  int kq = v >> 1, h = v & 1;
  int tok = toks[b*SS + c*128 + row];
  const float* src = emb + (size_t)tok*DD + kc*32 + kq*8;
  unsigned short o[8];
  #pragma unroll
  for (int j=0;j<8;j++){
    float f = src[j];
    unsigned short hi = f2bf(f);
    o[j] = h ? f2bf(f - bf2f(hi)) : hi;
  }
  ushort4* dst = (ushort4*)(xp + (size_t)id*8);
  dst[0] = make_ushort4(o[0],o[1],o[2],o[3]);
  dst[1] = make_ushort4(o[4],o[5],o[6],o[7]);
}

// ---------------- K2: summary = mean_s emb[toks] ----------------
__global__ __launch_bounds__(512) void colsum_part(const int* __restrict__ toks,
    const float* __restrict__ emb, float* __restrict__ part){
  int b = blockIdx.y, j = blockIdx.x, d = threadIdx.x;
  float s = 0.f;
  for (int k=0;k<64;k++){
    int tok = toks[b*SS + j*64 + k];
    s += emb[(size_t)tok*DD + d];
  }
  part[(b*16 + j)*DD + d] = s;
}
__global__ __launch_bounds__(512) void colsum_final(const float* __restrict__ part,
                                                    float* __restrict__ summary){
  int b = blockIdx.x, d = threadIdx.x;
  float s = 0.f;
  for (int j=0;j<16;j++) s += part[(b*16 + j)*DD + d];
  summary[b*DD + d] = s * (1.0f/1024.0f);
}

// ---------------- K3: gate MLP ----------------
__global__ __launch_bounds__(128) void gate_h1(const float* __restrict__ summary,
                                               const float* __restrict__ Wg1,
                                               const float* __restrict__ bg1,
                                               float* __restrict__ h1){
  int t = threadIdx.x; int j = blockIdx.x*128 + t;
  __shared__ float sm[16*512];
  for (int idx=t; idx<8192; idx+=128) sm[idx] = summary[idx];
  __syncthreads();
  float acc[16] = {0};
  for (int d=0; d<DD; d++){
    float w = Wg1[d*DD + j];
    #pragma unroll
    for (int b2=0;b2<16;b2++) acc[b2] += sm[b2*DD + d]*w;
  }
  #pragma unroll
  for (int b2=0;b2<16;b2++){ float v = acc[b2] + bg1[j]; h1[b2*DD + j] = v*sigm(v); }
}
__global__ __launch_bounds__(128) void gate_probs_k(const float* __restrict__ h1,
                                                    const float* __restrict__ Wg2,
                                                    const float* __restrict__ bg2,
                                                    float* __restrict__ gate){
  int t = threadIdx.x;         // 128 = 16 b x 8 e
  int b = t>>3, e = t&7;
  float acc = bg2[e];
  for (int d=0; d<DD; d++) acc += h1[b*DD + d]*Wg2[d*EE + e];
  __shared__ float lg[16][8];
  lg[b][e] = acc;
  __syncthreads();
  if (e==0){
    float m = -3.4e38f;
    for (int i=0;i<8;i++) m = fmaxf(m, lg[b][i]);
    float s = 0.f; float ex[8];
    for (int i=0;i<8;i++){ ex[i] = expf(lg[b][i]-m); s += ex[i]; }
    for (int i=0;i<8;i++) gate[b*EE + i] = ex[i]/s;
  }
}

// ---------------- W packers: f32 [e][k][c] -> staging images ----------------
// WPackAU: per (ec = e*8+ctile, kc): 1024 blocks [a(Ah,Al,Uh,Ul)][kq(4)][c(64)][8k]
__global__ __launch_bounds__(256) void convT_pack_au(const float* __restrict__ Wa,
    const float* __restrict__ Wu, unsigned short* __restrict__ WPackAU){
  const int ec = blockIdx.x;      // 64
  const int kc = blockIdx.y;      // 16
  const int e = ec >> 3, ct = ec & 7;
  __shared__ float ta[32][64];
  __shared__ float tu[32][64];
  const int t = threadIdx.x;
  for (int i=0;i<8;i++){
    int id = t + i*256;           // 2048
    int c = id & 63, kk = id >> 6;
    size_t src = ((size_t)e*DD + kc*32 + kk)*HH + ct*64 + c;
    ta[kk][c] = Wa[src];
    tu[kk][c] = Wu[src];
  }
  __syncthreads();
  unsigned short* o = WPackAU + ((size_t)ec*16 + kc)*8192;
  for (int i=0;i<8;i++){
    int idx4 = t + i*256;         // 2048 ushort4 units
    int blk = idx4 >> 1, half = idx4 & 1;
    int a = blk >> 8, kq = (blk >> 6) & 3, c = blk & 63;
    const float* src = (a >> 1) ? &tu[0][0] : &ta[0][0];
    unsigned short s4[4];
    #pragma unroll
    for (int j2=0;j2<4;j2++){
      int j = half*4 + j2;
      float f = src[(kq*8 + j)*64 + c];
      unsigned short hi = f2bf(f);
      s4[j2] = (a & 1) ? f2bf(f - bf2f(hi)) : hi;
    }
    *(ushort4*)&o[(size_t)idx4*4] = make_ushort4(s4[0],s4[1],s4[2],s4[3]);
  }
}
// WPackG: per (gt, kc): 512 blocks [a(hi,lo)][kq(4)][c(64)][8k]; gcol = gt*64+c -> (ee,r)
__global__ __launch_bounds__(256) void convT_pack_g(const float* __restrict__ Wge,
    unsigned short* __restrict__ WPackG){
  const int gt = blockIdx.x;      // 4
  const int kc = blockIdx.y;      // 16
  __shared__ float tg[32][64];
  const int t = threadIdx.x;
  for (int i=0;i<8;i++){
    int id = t + i*256;
    int c = id & 63, kk = id >> 6;
    int gcol = gt*64 + c;
    tg[kk][c] = Wge[((size_t)(gcol>>5)*DD + kc*32 + kk)*RR + (gcol & 31)];
  }
  __syncthreads();
  unsigned short* o = WPackG + ((size_t)gt*16 + kc)*4096;
  for (int i=0;i<4;i++){
    int idx4 = t + i*256;         // 1024 ushort4 units
    int blk = idx4 >> 1, half = idx4 & 1;
    int a = blk >> 8, kq = (blk >> 6) & 3, c = blk & 63;
    unsigned short s4[4];
    #pragma unroll
    for (int j2=0;j2<4;j2++){
      int j = half*4 + j2;
      float f = tg[kq*8 + j][c];
      unsigned short hi = f2bf(f);
      s4[j2] = a ? f2bf(f - bf2f(hi)) : hi;
    }
    *(ushort4*)&o[(size_t)idx4*4] = make_ushort4(s4[0],s4[1],s4[2],s4[3]);
  }
}

// ---------------- fused AUG(c) + scan(c-1), 2-phase dbuf staging ----------------
// blocks 0..127: scan (e,b). blocks 128..1215: aug: aid=bid-128, b=aid&15, ct=aid>>4.
//   ct<64: A+U tile (e=ct>>3, ctile=ct&7); ct 64..67: G tile
__global__ __launch_bounds__(512, 2) void aug_scan(
    const unsigned short* __restrict__ xp,
    const unsigned short* __restrict__ WPackAU, const unsigned short* __restrict__ WPackG,
    const float* __restrict__ ba, const float* __restrict__ bu, const float* __restrict__ bge,
    float* __restrict__ Aw, float* __restrict__ Uw, float* __restrict__ Gw,
    const float* __restrict__ Ar, const float* __restrict__ Ur, const float* __restrict__ Gr,
    const float* __restrict__ v_mat, const float* __restrict__ u_mat,
    float* __restrict__ states,
    int s0, int do_aug, int do_scan)
{
  __shared__ __align__(16) unsigned short lds[32768];   // 64 KB: 2 bufs x (16KB X + 16KB W)
  const int t = threadIdx.x;

  if (blockIdx.x < 128){
    // ================= scan path (2 barriers/step, wave-local phase B) =================
    if (!do_scan) return;
    const int e = blockIdx.x >> 4;
    const int b = blockIdx.x & 15;
    const int r = t & 31, grp = t >> 5;     // 32 r x 16 groups
    const int lane = t & 63, wv = t >> 6;
    float* stf   = (float*)lds;             // [2][512]
    float* partf = (float*)lds + 1024;      // [32][9]
    float* lowf  = (float*)lds + 1312;      // [8 waves][32]
    float vreg[32];
    #pragma unroll
    for (int i=0;i<32;i++) vreg[i] = v_mat[((size_t)e*HH + grp*32 + i)*RR + r];
    float ureg[32];
    {
      const float4* up = (const float4*)(u_mat + ((size_t)e*HH + t)*RR);
      #pragma unroll
      for (int j=0;j<8;j++){
        float4 v4 = up[j];
        ureg[j*4+0]=v4.x; ureg[j*4+1]=v4.y; ureg[j*4+2]=v4.z; ureg[j*4+3]=v4.w;
      }
    }
    const size_t base  = ((size_t)e*BB + b)*HH + t;
    const size_t gbase = ((size_t)e*BB + b)*RR + r;
    const size_t strAU = (size_t)EE*BB*HH;
    const size_t strG  = (size_t)EE*BB*RR;
    float streg = states[base];
    stf[t] = streg;
    float a0 = Ar[base], u0 = Ur[base];
    float g0 = (lane < 32) ? Gr[gbase] : 0.f;
    float a1 = Ar[base + strAU], u1 = Ur[base + strAU];
    float g1 = (lane < 32) ? Gr[gbase + strG] : 0.f;
    __syncthreads();
    int cur = 0;
    for (int s=0; s<SCH; s++){
      float a2 = 0.f, u2 = 0.f, g2 = 0.f;
      if (s+2 < SCH){
        a2 = Ar[base + (size_t)(s+2)*strAU];
        u2 = Ur[base + (size_t)(s+2)*strAU];
        if (lane < 32) g2 = Gr[gbase + (size_t)(s+2)*strG];
      }
      // phase A: partials of v^T state; fold grp pairs in-wave -> partf[r][wv]
      float p = 0.f;
      #pragma unroll
      for (int i=0;i<32;i++) p += stf[cur*512 + grp*32+i]*vreg[i];
      p += __shfl_xor(p, 32, 64);
      if ((t & 32) == 0) partf[r*9 + wv] = p;
      __syncthreads();                         // B1: partf visible to all waves
      // phase B (wave-local, redundant per wave; no barrier)
      if (lane < 32){
        float ss2 = 0.f;
        #pragma unroll
        for (int j=0;j<8;j++) ss2 += partf[lane*9 + j];
        lowf[wv*32 + lane] = ss2 * g0;
      }
      // phase C (reads own wave's lowf slot; intra-wave lgkmcnt ordering)
      {
        const float* lw = &lowf[wv*32];
        float acc2 = 0.f;
        #pragma unroll
        for (int i=0;i<32;i++) acc2 += lw[i]*ureg[i];
        streg = a0*streg + u0 + acc2;
      }
      stf[(cur^1)*512 + t] = streg;
      cur ^= 1;
      a0=a1; u0=u1; g0=g1; a1=a2; u1=u2; g1=g2;
      __syncthreads();                         // B2: stf visible for next phase A
    }
    states[base] = streg;
    return;
  }

  // ================= aug path =================
  if (!do_aug) return;
  const int aid = blockIdx.x - 128;
  const int b  = aid & 15;
  const int ct = aid >> 4;          // 0..67
  const int lane = t & 63, wv = t >> 6;
  const int cix = s0 >> 7;
  const unsigned short* xpc = xp + (((size_t)(b*8 + cix)) << 17);
  const int wo = wv*64;

  f32x4 acc[2][4] = {};
  const int cl15 = lane & 15;

  if (ct < 64){
    // ---- A+U tile: waves 0-3 = A strips, 4-7 = U strips ----
    const int e = ct >> 3;
    const int c0 = (ct & 7)*64;
    const unsigned short* wpc = WPackAU + (((size_t)ct) << 17);
    const int strip = wv & 3;
    const int mode  = wv >> 2;
    const int kq4 = lane >> 4;
    const int rr0 = strip*32 + cl15, rr1 = rr0 + 16;
    const int qh = (kq4*2) ^ (rr0 & 7);
    const int ql = (kq4*2+1) ^ (rr0 & 7);
    const int ab = mode*512;

#define STAGE_AU(BUF, KC) { \
    unsigned short* XB_ = lds + (BUF)*16384; \
    unsigned short* WB_ = XB_ + 8192; \
    const unsigned short* gx = xpc + (KC)*8192; \
    const unsigned short* gw = wpc + (KC)*8192; \
    gload16(XB_ + wo*8,        gx + (size_t)(wo + lane)*8); \
    gload16(XB_ + (512+wo)*8,  gx + (size_t)(512 + wo + lane)*8); \
    gload16(WB_ + wo*8,        gw + (size_t)(wo + lane)*8); \
    gload16(WB_ + (512+wo)*8,  gw + (size_t)(512 + wo + lane)*8); }

    STAGE_AU(0, 0)
    asm volatile("s_waitcnt vmcnt(0)" ::: "memory");
    __builtin_amdgcn_s_barrier();
    __builtin_amdgcn_sched_barrier(0);
    int cur = 0;
    for (int kc=0; kc<16; kc++){
      if (kc < 15) STAGE_AU(cur^1, kc+1)
      const unsigned short* XB = lds + cur*16384;
      const unsigned short* WB = XB + 8192;
      bf16x8 ah0 = *(const bf16x8*)&XB[(rr0*8 + qh)*8];
      bf16x8 al0 = *(const bf16x8*)&XB[(rr0*8 + ql)*8];
      bf16x8 ah1 = *(const bf16x8*)&XB[(rr1*8 + qh)*8];
      bf16x8 al1 = *(const bf16x8*)&XB[(rr1*8 + ql)*8];
      #pragma unroll
      for (int cf=0; cf<4; cf++){
        const int cc = cf*16 + cl15;
        bf16x8 bh = *(const bf16x8*)&WB[(ab + kq4*64 + cc)*8];
        bf16x8 bl = *(const bf16x8*)&WB[(ab + 256 + kq4*64 + cc)*8];
        acc[0][cf] = __builtin_amdgcn_mfma_f32_16x16x32_bf16(ah0, bh, acc[0][cf], 0,0,0);
        acc[0][cf] = __builtin_amdgcn_mfma_f32_16x16x32_bf16(ah0, bl, acc[0][cf], 0,0,0);
        acc[0][cf] = __builtin_amdgcn_mfma_f32_16x16x32_bf16(al0, bh, acc[0][cf], 0,0,0);
        acc[1][cf] = __builtin_amdgcn_mfma_f32_16x16x32_bf16(ah1, bh, acc[1][cf], 0,0,0);
        acc[1][cf] = __builtin_amdgcn_mfma_f32_16x16x32_bf16(ah1, bl, acc[1][cf], 0,0,0);
        acc[1][cf] = __builtin_amdgcn_mfma_f32_16x16x32_bf16(al1, bh, acc[1][cf], 0,0,0);
      }
      __builtin_amdgcn_sched_barrier(0);
      asm volatile("s_waitcnt vmcnt(0)" ::: "memory");
      __builtin_amdgcn_s_barrier();
      __builtin_amdgcn_sched_barrier(0);
      cur ^= 1;
    }
#undef STAGE_AU
    // epilogue: C/D col=lane&15, row=(lane>>4)*4+reg
    const int r4 = (lane >> 4) * 4;
    #pragma unroll
    for (int rf=0; rf<2; rf++){
      #pragma unroll
      for (int cf=0; cf<4; cf++){
        #pragma unroll
        for (int i=0;i<4;i++){
          int sl = strip*32 + rf*16 + r4 + i;
          int ce = c0 + cf*16 + cl15;
          float v = acc[rf][cf][i];
          if (mode == 0){
            v += ba[e*HH + ce];
            v = sigm(v);
            Aw[((size_t)(sl*EE + e)*BB + b)*HH + ce] = v;
          } else {
            v += bu[e*HH + ce];
            Uw[((size_t)(sl*EE + e)*BB + b)*HH + ce] = v;
          }
        }
      }
    }
  } else {
    // ---- G tile: 8 waves x 16 rows ----
    const int gt = ct - 64;
    const int c0 = gt*64;
    const unsigned short* wpc = WPackG + (((size_t)gt) << 16);
    const int kq4 = lane >> 4;
    const int rr0 = wv*16 + cl15;
    const int qh = (kq4*2) ^ (rr0 & 7);
    const int ql = (kq4*2+1) ^ (rr0 & 7);

#define STAGE_G(BUF, KC) { \
    unsigned short* XB_ = lds + (BUF)*16384; \
    unsigned short* WB_ = XB_ + 8192; \
    const unsigned short* gx = xpc + (KC)*8192; \
    const unsigned short* gw = wpc + (KC)*4096; \
    gload16(XB_ + wo*8,        gx + (size_t)(wo + lane)*8); \
    gload16(XB_ + (512+wo)*8,  gx + (size_t)(512 + wo + lane)*8); \
    gload16(WB_ + wo*8,        gw + (size_t)(wo + lane)*8); }

    STAGE_G(0, 0)
    asm volatile("s_waitcnt vmcnt(0)" ::: "memory");
    __builtin_amdgcn_s_barrier();
    __builtin_amdgcn_sched_barrier(0);
    int cur = 0;
    for (int kc=0; kc<16; kc++){
      if (kc < 15) STAGE_G(cur^1, kc+1)
      const unsigned short* XB = lds + cur*16384;
      const unsigned short* WB = XB + 8192;
      bf16x8 ah0 = *(const bf16x8*)&XB[(rr0*8 + qh)*8];
      bf16x8 al0 = *(const bf16x8*)&XB[(rr0*8 + ql)*8];
      #pragma unroll
      for (int cf=0; cf<4; cf++){
        const int cc = cf*16 + cl15;
        bf16x8 bh = *(const bf16x8*)&WB[(kq4*64 + cc)*8];
        bf16x8 bl = *(const bf16x8*)&WB[(256 + kq4*64 + cc)*8];
        acc[0][cf] = __builtin_amdgcn_mfma_f32_16x16x32_bf16(ah0, bh, acc[0][cf], 0,0,0);
        acc[0][cf] = __builtin_amdgcn_mfma_f32_16x16x32_bf16(ah0, bl, acc[0][cf], 0,0,0);
        acc[0][cf] = __builtin_amdgcn_mfma_f32_16x16x32_bf16(al0, bh, acc[0][cf], 0,0,0);
      }
      __builtin_amdgcn_sched_barrier(0);
      asm volatile("s_waitcnt vmcnt(0)" ::: "memory");
      __builtin_amdgcn_s_barrier();
      __builtin_amdgcn_sched_barrier(0);
      cur ^= 1;
    }
#undef STAGE_G
    const int r4 = (lane >> 4) * 4;
    #pragma unroll
    for (int cf=0; cf<4; cf++){
      #pragma unroll
      for (int i=0;i<4;i++){
        int sl = wv*16 + r4 + i;
        int g = c0 + cf*16 + cl15;
        int ee = g >> 5, r2 = g & 31;
        float v = acc[0][cf][i] + bge[ee*RR + r2];
        Gw[((size_t)(sl*EE + ee)*BB + b)*RR + r2] = v;
      }
    }
  }
}

// ---------------- K5: proj + gate-weighted fuse ----------------
__global__ __launch_bounds__(128) void proj_partial(const float* __restrict__ states,
    const float* __restrict__ Wp, const float* __restrict__ gate, float* __restrict__ pf){
  int fc = blockIdx.x, e = blockIdx.y, t = threadIdx.x;
  __shared__ float stl[16*512];
  for (int idx=t; idx<8192; idx+=128) stl[idx] = states[(size_t)e*8192 + idx];
  __syncthreads();
  int f = fc*128 + t;
  float acc[16] = {0};
  for (int h=0; h<HH; h++){
    float w = Wp[((size_t)e*HH + h)*FF + f];
    #pragma unroll
    for (int b2=0;b2<16;b2++) acc[b2] += stl[b2*HH + h]*w;
  }
  #pragma unroll
  for (int b2=0;b2<16;b2++) pf[((size_t)(e*16 + b2))*FF + f] = gate[b2*EE + e]*acc[b2];
}
__global__ __launch_bounds__(256) void fuse_reduce(const float* __restrict__ pf,
    const float* __restrict__ gate, const float* __restrict__ bp, float* __restrict__ fused){
  int idx = blockIdx.x*256 + threadIdx.x;     // 16*1024
  int b = idx >> 10, f = idx & 1023;
  float s = 0.f;
  #pragma unroll
  for (int e=0;e<8;e++) s += pf[((size_t)(e*16 + b))*FF + f] + gate[b*EE + e]*bp[e*FF + f];
  fused[idx] = s;
}

// ---------------- fq_linear: out = fake_quantize(in @ W + bias) ----------------
__global__ __launch_bounds__(128) void fq_linear(const float* __restrict__ in, int Kin,
    const float* __restrict__ W, const float* __restrict__ bias, float* __restrict__ out){
  int b = blockIdx.x, t = threadIdx.x;
  __shared__ float xin[1024];
  __shared__ float red[2];
  for (int k=t;k<Kin;k+=128) xin[k] = in[(size_t)b*Kin + k];
  __syncthreads();
  float acc = bias[t];
  for (int k=0;k<Kin;k++) acc += xin[k]*W[k*QQ + t];
  float ss = acc*acc;
  #pragma unroll
  for (int off=32; off; off>>=1) ss += __shfl_xor(ss, off, 64);
  if ((t&63)==0) red[t>>6] = ss;
  __syncthreads();
  float n = fmaxf(sqrtf(red[0]+red[1]), 1e-6f);
  float xn = acc / n;
  float q = fminf(fmaxf(rintf(xn*127.0f), -127.0f), 127.0f) * (1.0f/127.0f);
  out[b*QQ + t] = q;
}

// ---------------- K7: chunk/next embedding means -> t_in ----------------
__global__ __launch_bounds__(512) void chunk_means(const int* __restrict__ ct,
    const int* __restrict__ nct, const float* __restrict__ emb, float* __restrict__ tin){
  int b = blockIdx.x, d = threadIdx.x;
  float ce=0.f, ne=0.f;
  for (int c=0;c<CC;c++){
    ce += emb[(size_t)ct[b*CC+c]*DD + d];
    ne += emb[(size_t)nct[b*CC+c]*DD + d];
  }
  tin[b*1024 + d] = ce*0.125f;
  tin[b*1024 + 512 + d] = ne*0.125f;
}

// ---------------- K8: target_state ----------------
__global__ __launch_bounds__(512) void target_state_kernel(const float* __restrict__ tin,
    const float* __restrict__ Wt1, const float* __restrict__ bt1,
    const float* __restrict__ Wt2, const float* __restrict__ bt2, float* __restrict__ outts){
  int b = blockIdx.x, t = threadIdx.x;   // 512
  __shared__ float xin[1024];
  __shared__ float h1[512];
  __shared__ float red[8];
  for (int k=t;k<1024;k+=512) xin[k] = tin[b*1024 + k];
  __syncthreads();
  float acc = bt1[t];
  for (int k=0;k<1024;k++) acc += xin[k]*Wt1[k*RTd + t];
  acc = acc*sigm(acc);
  h1[t] = acc;
  __syncthreads();
  float y = bt2[t];
  for (int k=0;k<512;k++) y += h1[k]*Wt2[k*RTd + t];
  float ss = y*y;
  #pragma unroll
  for (int off=32; off; off>>=1) ss += __shfl_xor(ss, off, 64);
  if ((t&63)==0) red[t>>6] = ss;
  __syncthreads();
  float tot = 0.f;
  #pragma unroll
  for (int i=0;i<8;i++) tot += red[i];
  float n = fmaxf(sqrtf(tot), 1e-6f);
  outts[b*RTd + t] = y/n;
}

// ---------------- K11: write_state = normalize((ctx@Wwc+bwc)@Web) ----------------
__global__ __launch_bounds__(512) void write_state_kernel(const float* __restrict__ ctx,
    const float* __restrict__ Wwc, const float* __restrict__ bwc,
    const float* __restrict__ Web, float* __restrict__ wsn){
  int b = blockIdx.x, t = threadIdx.x;   // 512
  __shared__ float cx[1024];
  __shared__ float wc[64];
  __shared__ float red[8];
  for (int k=t;k<1024;k+=512) cx[k] = ctx[b*FF + k];
  __syncthreads();
  if (t < 64){
    float a = bwc[t];
    for (int k=0;k<1024;k++) a += cx[k]*Wwc[k*CDd + t];
    wc[t] = a;
  }
  __syncthreads();
  float y = 0.f;
  for (int k=0;k<64;k++) y += wc[k]*Web[k*RTd + t];
  float ss = y*y;
  #pragma unroll
  for (int off=32; off; off>>=1) ss += __shfl_xor(ss, off, 64);
  if ((t&63)==0) red[t>>6] = ss;
  __syncthreads();
  float tot = 0.f;
  #pragma unroll
  for (int i=0;i<8;i++) tot += red[i];
  float n = fmaxf(sqrtf(tot), 1e-6f);
  wsn[b*RTd + t] = y/n;
}

// ---------------- K12: sim ----------------
__global__ __launch_bounds__(256) void sim_kernel(const float* __restrict__ q,
    const float* __restrict__ k, float* __restrict__ out){
  int t = threadIdx.x;
  int i = t>>4, j = t&15;
  float s = 0.f;
  for (int c=0;c<QQ;c++) s += q[i*QQ + c]*k[j*QQ + c];
  out[t] = s / sqrtf(128.0f);
}

// ---------------- K13pre: xcat = [emb[chunk_inputs], ctx] ----------------
__global__ __launch_bounds__(256) void build_xcat(const int* __restrict__ ci,
    const float* __restrict__ emb, const float* __restrict__ ctx, float* __restrict__ xcat){
  int idx = blockIdx.x*256 + threadIdx.x;   // 128*1536
  int row = idx / 1536, k = idx % 1536;
  float v = (k < DD) ? emb[(size_t)ci[row]*DD + k] : ctx[(row>>3)*FF + (k - DD)];
  xcat[idx] = v;
}

// ---------------- split-K partial GEMM (N=1024 outputs) ----------------
__global__ __launch_bounds__(256) void gemm_part(const float* __restrict__ X,
    const float* __restrict__ W, float* __restrict__ part,
    int K, int KS, int M){
  const int t = threadIdx.x;
  const int col = blockIdx.x*64 + (t & 63);
  const int r0 = blockIdx.y*16;
  const int ks = blockIdx.z;
  const int rg = t >> 6;           // 4 groups x 4 rows
  const int kslice = K / KS;
  const int kbeg = ks*kslice;
  __shared__ float xs[16][65];
  float acc[4] = {};
  for (int k0=kbeg; k0<kbeg+kslice; k0+=64){
    #pragma unroll
    for (int i=0;i<4;i++){
      int id = t + i*256;
      int row = id >> 6, kk = id & 63;
      xs[row][kk] = X[(size_t)(r0+row)*K + k0 + kk];
    }
    __syncthreads();
    #pragma unroll 8
    for (int kk=0; kk<64; kk++){
      float w = W[(size_t)(k0+kk)*FF + col];
      #pragma unroll
      for (int i=0;i<4;i++) acc[i] += xs[rg*4+i][kk]*w;
    }
    __syncthreads();
  }
  #pragma unroll
  for (int i=0;i<4;i++)
    part[((size_t)ks*M + r0 + rg*4 + i)*FF + col] = acc[i];
}
__global__ __launch_bounds__(256) void gemm_combine(const float* __restrict__ part,
    const float* __restrict__ bias, const float* __restrict__ pos,
    float* __restrict__ outp, int KS, int M, int act){
  int idx = blockIdx.x*256 + threadIdx.x;     // M*1024
  int row = idx >> 10, col = idx & 1023;
  float v = bias[col];
  for (int k=0;k<KS;k++) v += part[(size_t)k*M*FF + idx];
  if (pos) v += pos[(row & 7)*FF + col];
  if (act) v = v*sigm(v);
  outp[idx] = v;
}

// ---------------- split hidden for logits ----------------
__global__ __launch_bounds__(256) void split_h(const float* __restrict__ hsrc,
    unsigned short* __restrict__ hh, unsigned short* __restrict__ hl){
  int idx = blockIdx.x*256 + threadIdx.x;   // 131072
  float f = hsrc[idx];
  unsigned short h = f2bf(f);
  hh[idx] = h;
  hl[idx] = f2bf(f - bf2f(h));
}

// ---------------- K15: logits via split-bf16 MFMA ----------------
__global__ __launch_bounds__(256) void logits_mfma(
    const unsigned short* __restrict__ hh, const unsigned short* __restrict__ hl,
    const float* __restrict__ Wlm, const float* __restrict__ blm,
    float* __restrict__ out){
  const int t = threadIdx.x;
  const int lane = t & 63, w = t >> 6;
  const int cb = blockIdx.x * 64;
  __shared__ __align__(16) unsigned short xsh[8*128*8];   // block = row*8 + (kq^(row&7))
  __shared__ __align__(16) unsigned short xsl[8*128*8];
  __shared__ __align__(16) unsigned short wsh[8*64*8];    // block = kq*64 + cc (linear)
  __shared__ __align__(16) unsigned short wsl[8*64*8];
  f32x4 acc[2][4] = {};
  for (int kc=0; kc<16; kc++){
    const int k0 = kc*64;
    #pragma unroll
    for (int i=0;i<4;i++){
      int id = t + i*256;
      int kq = id & 7, row = id >> 3;
      int pb = row*8 + (kq ^ (row&7));
      *(uint4*)&xsh[pb*8] = *(const uint4*)(hh + (size_t)row*FF + k0 + kq*8);
      *(uint4*)&xsl[pb*8] = *(const uint4*)(hl + (size_t)row*FF + k0 + kq*8);
    }
    #pragma unroll
    for (int i=0;i<2;i++){
      int id = t + i*256;
      int cc = id & 63, kq = id >> 6;
      int c = cb + cc; if (c >= VV) c = VV - 1;
      unsigned short h8[8], l8[8];
      #pragma unroll
      for (int j=0;j<8;j++){
        float f = Wlm[(size_t)(k0 + kq*8 + j)*VV + c];
        unsigned short h = f2bf(f);
        h8[j] = h;
        l8[j] = f2bf(f - bf2f(h));
      }
      int pb = kq*64 + cc;
      *(ushort4*)&wsh[pb*8]   = make_ushort4(h8[0],h8[1],h8[2],h8[3]);
      *(ushort4*)&wsh[pb*8+4] = make_ushort4(h8[4],h8[5],h8[6],h8[7]);
      *(ushort4*)&wsl[pb*8]   = make_ushort4(l8[0],l8[1],l8[2],l8[3]);
      *(ushort4*)&wsl[pb*8+4] = make_ushort4(l8[4],l8[5],l8[6],l8[7]);
    }
    __syncthreads();
    #pragma unroll
    for (int ks=0; ks<2; ks++){
      const int kq4 = ks*4 + (lane>>4);
      const int rr0 = w*32 + (lane&15);
      const int rr1 = rr0 + 16;
      bf16x8 ah0 = *(const bf16x8*)&xsh[(rr0*8 + (kq4^(rr0&7)))*8];
      bf16x8 ah1 = *(const bf16x8*)&xsh[(rr1*8 + (kq4^(rr1&7)))*8];
      bf16x8 al0 = *(const bf16x8*)&xsl[(rr0*8 + (kq4^(rr0&7)))*8];
      bf16x8 al1 = *(const bf16x8*)&xsl[(rr1*8 + (kq4^(rr1&7)))*8];
      #pragma unroll
      for (int cf=0; cf<4; cf++){
        const int cc = cf*16 + (lane&15);
        bf16x8 bh = *(const bf16x8*)&wsh[(kq4*64 + cc)*8];
        bf16x8 bl = *(const bf16x8*)&wsl[(kq4*64 + cc)*8];
        acc[0][cf] = __builtin_amdgcn_mfma_f32_16x16x32_bf16(ah0, bh, acc[0][cf], 0,0,0);
        acc[0][cf] = __builtin_amdgcn_mfma_f32_16x16x32_bf16(ah0, bl, acc[0][cf], 0,0,0);
        acc[0][cf] = __builtin_amdgcn_mfma_f32_16x16x32_bf16(al0, bh, acc[0][cf], 0,0,0);
        acc[1][cf] = __builtin_amdgcn_mfma_f32_16x16x32_bf16(ah1, bh, acc[1][cf], 0,0,0);
        acc[1][cf] = __builtin_amdgcn_mfma_f32_16x16x32_bf16(ah1, bl, acc[1][cf], 0,0,0);
        acc[1][cf] = __builtin_amdgcn_mfma_f32_16x16x32_bf16(al1, bh, acc[1][cf], 0,0,0);
      }
    }
    __syncthreads();
  }
  const int cl = lane & 15;
  const int r4 = (lane >> 4) * 4;
  #pragma unroll
  for (int rf=0; rf<2; rf++){
    #pragma unroll
    for (int cf=0; cf<4; cf++){
      int c = cb + cf*16 + cl;
      if (c >= VV) continue;
      float bb = blm[c];
      #pragma unroll
      for (int i=0;i<4;i++){
        int row = w*32 + rf*16 + r4 + i;
        out[(size_t)row*VV + c] = acc[rf][cf][i] + bb;
      }
    }
  }
}

// ---------------- K16: online per-row logsumexp + NLL ----------------
__global__ __launch_bounds__(512) void softmax_nll(const float* __restrict__ logits,
    const int* __restrict__ tgt, float* __restrict__ tl){
  const int row = blockIdx.x;
  const float* p = logits + (size_t)row*VV;
  const int t = threadIdx.x;
  float m = -3.4e38f, s = 0.f;
  for (int c=t; c<VV; c+=512){
    float v = p[c];
    if (v > m){ s = s*expf(m - v) + 1.0f; m = v; }
    else s += expf(v - m);
  }
  #pragma unroll
  for (int off=32; off; off>>=1){
    float m2 = __shfl_xor(m, off, 64);
    float s2 = __shfl_xor(s, off, 64);
    float mn = fmaxf(m, m2);
    s = s*expf(m - mn) + s2*expf(m2 - mn);
    m = mn;
  }
  __shared__ float ms[8], ssh[8];
  if ((t&63)==0){ ms[t>>6] = m; ssh[t>>6] = s; }
  __syncthreads();
  if (t==0){
    float M = ms[0], S = ssh[0];
    for (int i=1;i<8;i++){
      float mn = fmaxf(M, ms[i]);
      S = S*expf(M-mn) + ssh[i]*expf(ms[i]-mn);
      M = mn;
    }
    tl[row] = M + logf(S) - p[tgt[row]];
  }
}
__global__ __launch_bounds__(128) void loss_reduce(const float* __restrict__ tl,
                                                   float* __restrict__ out){
  int t = threadIdx.x;
  float v = tl[t];
  #pragma unroll
  for (int off=32; off; off>>=1) v += __shfl_xor(v, off, 64);
  __shared__ float r2[2];
  if ((t&63)==0) r2[t>>6] = v;
  __syncthreads();
  if (t==0) out[0] = (r2[0]+r2[1]) * (1.0f/128.0f);
}

// =======================================================================
extern "C" void kernel_launch(void* const* d_in, const int* in_sizes, int n_in,
                              void* d_out, int out_size, void* d_ws, size_t ws_size,
                              hipStream_t stream){
  (void)in_sizes; (void)n_in; (void)out_size;
  const int*  prefix = (const int*)d_in[0];
  const int*  cinp   = (const int*)d_in[1];
  const int*  ctgt   = (const int*)d_in[2];
  const int*  nctk   = (const int*)d_in[3];
  const float* emb  = (const float*)d_in[4];
  const float* Wa   = (const float*)d_in[5];
  const float* ba   = (const float*)d_in[6];
  const float* Wge  = (const float*)d_in[7];
  const float* bge  = (const float*)d_in[8];
  const float* Wu   = (const float*)d_in[9];
  const float* bu   = (const float*)d_in[10];
  const float* u_mat= (const float*)d_in[11];
  const float* v_mat= (const float*)d_in[12];
  const float* Wp   = (const float*)d_in[13];
  const float* bp   = (const float*)d_in[14];
  const float* Wg1  = (const float*)d_in[15];
  const float* bg1  = (const float*)d_in[16];
  const float* Wg2  = (const float*)d_in[17];
  const float* bg2  = (const float*)d_in[18];
  const float* Wq   = (const float*)d_in[19];
  const float* bq   = (const float*)d_in[20];
  const float* Wt1  = (const float*)d_in[21];
  const float* bt1  = (const float*)d_in[22];
  const float* Wt2  = (const float*)d_in[23];
  const float* bt2  = (const float*)d_in[24];
  const float* Wk   = (const float*)d_in[25];
  const float* bk   = (const float*)d_in[26];
  const float* Web  = (const float*)d_in[27];
  const float* Wwc  = (const float*)d_in[28];
  const float* bwc  = (const float*)d_in[29];
  const float* Wc1  = (const float*)d_in[30];
  const float* bc1  = (const float*)d_in[31];
  const float* Wc2  = (const float*)d_in[32];
  const float* bc2  = (const float*)d_in[33];
  const float* cpos = (const float*)d_in[34];
  const float* Wci  = (const float*)d_in[35];
  const float* bci  = (const float*)d_in[36];
  const float* Wm1  = (const float*)d_in[37];
  const float* bm1  = (const float*)d_in[38];
  const float* Wm2  = (const float*)d_in[39];
  const float* bm2  = (const float*)d_in[40];
  const float* Wlm  = (const float*)d_in[41];
  const float* blm  = (const float*)d_in[42];

  float* ws = (float*)d_ws;
  size_t off = 0;
  unsigned short* xp = (unsigned short*)(ws + off); off += (size_t)BB*SS*DD;   // hi+lo packed, 33.5 MB
  float* Abuf0  = ws + off; off += (size_t)SCH*EE*BB*HH;
  float* Ubuf0  = ws + off; off += (size_t)SCH*EE*BB*HH;
  float* Gbuf0  = ws + off; off += (size_t)SCH*EE*BB*RR;
  float* statesb= ws + off; off += (size_t)EE*BB*HH;
  float* partb  = ws + off; off += (size_t)BB*16*DD;
  float* summb  = ws + off; off += (size_t)BB*DD;
  float* h1b    = ws + off; off += (size_t)BB*DD;
  float* gateb  = ws + off; off += (size_t)BB*EE;
  float* pfb    = ws + off; off += (size_t)EE*BB*FF;
  float* fusedb = ws + off; off += (size_t)BB*FF;
  float* qstb   = ws + off; off += (size_t)BB*QQ;
  float* tinb   = ws + off; off += (size_t)BB*2*DD;
  float* tstb   = ws + off; off += (size_t)BB*RTd;
  float* tkb    = ws + off; off += (size_t)BB*QQ;
  float* ctxb   = ws + off; off += (size_t)BB*FF;
  float* hctxb  = ws + off; off += (size_t)BB*FF;
  float* wsnb   = ws + off; off += (size_t)BB*RTd;
  float* xcatb  = ws + off; off += (size_t)BB*CC*(DD+FF);
  float* hid1b  = ws + off; off += (size_t)BB*CC*FF;
  float* h2b    = ws + off; off += (size_t)BB*CC*FF;
  float* hidb   = ws + off; off += (size_t)BB*CC*FF;
  float* tlb    = ws + off; off += (size_t)BB*CC;
  float* ppart  = ws + off; off += (size_t)4*BB*CC*FF;
  unsigned short* WPackAU = (unsigned short*)(ws + off); off += (size_t)EE*DD*HH*2;  // 16.7 MB
  unsigned short* WPackG  = (unsigned short*)(ws + off); off += (size_t)EE*DD*RR;
  unsigned short* hhb  = (unsigned short*)(ws + off); off += (size_t)BB*CC*FF/2;
  unsigned short* hlb  = (unsigned short*)(ws + off); off += (size_t)BB*CC*FF/2;
  // double-buffer extension (fused schedule only)
  float* Abuf1  = ws + off; off += (size_t)SCH*EE*BB*HH;
  float* Ubuf1  = ws + off; off += (size_t)SCH*EE*BB*HH;
  float* Gbuf1  = ws + off; off += (size_t)SCH*EE*BB*RR;
  const bool fused = ws_size >= off * sizeof(float);

  float* out = (float*)d_out;
  const size_t LOGITS_OFF = 0;
  const size_t LOSS_OFF = (size_t)BB*CC*VV;
  const size_t SIM_OFF  = LOSS_OFF + 1;
  const size_t WK_OFF   = SIM_OFF + (size_t)BB*BB;

  // ---- one-time weight packs (bf16 hi/lo, staging-image layout) ----
  convT_pack_au<<<dim3(64,16), 256, 0, stream>>>(Wa, Wu, WPackAU);
  convT_pack_g<<<dim3(4,16), 256, 0, stream>>>(Wge, WPackG);

  // ---- prefix encode ----
  gather_pack<<<8192, 256, 0, stream>>>(prefix, emb, xp);
  colsum_part<<<dim3(16,16), 512, 0, stream>>>(prefix, emb, partb);
  colsum_final<<<16, 512, 0, stream>>>(partb, summb);
  gate_h1<<<4, 128, 0, stream>>>(summb, Wg1, bg1, h1b);
  gate_probs_k<<<1, 128, 0, stream>>>(h1b, Wg2, bg2, gateb);

  hipMemsetAsync(statesb, 0, (size_t)EE*BB*HH*sizeof(float), stream);

  if (fused){
    for (int c=0; c<=8; c++){
      int da = (c<8) ? 1 : 0;
      int dscn = (c>=1) ? 1 : 0;
      float* Aw = (c&1) ? Abuf1 : Abuf0;
      float* Uw = (c&1) ? Ubuf1 : Ubuf0;
      float* Gw = (c&1) ? Gbuf1 : Gbuf0;
      const float* Ar = ((c-1)&1) ? Abuf1 : Abuf0;
      const float* Ur = ((c-1)&1) ? Ubuf1 : Ubuf0;
      const float* Gr = ((c-1)&1) ? Gbuf1 : Gbuf0;
      int grid = da ? 1216 : 128;
      aug_scan<<<grid, 512, 0, stream>>>(xp, WPackAU, WPackG, ba, bu, bge,
          Aw, Uw, Gw, Ar, Ur, Gr, v_mat, u_mat, statesb,
          c*SCH, da, dscn);
    }
  } else {
    for (int c=0; c<8; c++){
      aug_scan<<<1216, 512, 0, stream>>>(xp, WPackAU, WPackG, ba, bu, bge,
          Abuf0, Ubuf0, Gbuf0, Abuf0, Ubuf0, Gbuf0, v_mat, u_mat, statesb,
          c*SCH, 1, 0);
      aug_scan<<<128, 512, 0, stream>>>(xp, WPackAU, WPackG, ba, bu, bge,
          Abuf0, Ubuf0, Gbuf0, Abuf0, Ubuf0, Gbuf0, v_mat, u_mat, statesb,
          c*SCH, 0, 1);
    }
  }

  proj_partial<<<dim3(8,8), 128, 0, stream>>>(statesb, Wp, gateb, pfb);
  fuse_reduce<<<64, 256, 0, stream>>>(pfb, gateb, bp, fusedb);

  // ---- query / target / key ----
  fq_linear<<<16, 128, 0, stream>>>(fusedb, FF, Wq, bq, qstb);
  chunk_means<<<16, 512, 0, stream>>>(ctgt, nctk, emb, tinb);
  target_state_kernel<<<16, 512, 0, stream>>>(tinb, Wt1, bt1, Wt2, bt2, tstb);
  fq_linear<<<16, 128, 0, stream>>>(tstb, RTd, Wk, bk, tkb);

  // ---- read_context (split-K, M=16) ----
  gemm_part<<<dim3(16,1,4), 256, 0, stream>>>(fusedb, Wc1, ppart, FF, 4, 16);
  gemm_combine<<<64, 256, 0, stream>>>(ppart, bc1, nullptr, hctxb, 4, 16, 1);
  gemm_part<<<dim3(16,1,4), 256, 0, stream>>>(hctxb, Wc2, ppart, FF, 4, 16);
  gemm_combine<<<64, 256, 0, stream>>>(ppart, bc2, nullptr, ctxb, 4, 16, 0);

  // ---- write path ----
  write_state_kernel<<<16, 512, 0, stream>>>(ctxb, Wwc, bwc, Web, wsnb);
  fq_linear<<<16, 128, 0, stream>>>(wsnb, RTd, Wk, bk, out + WK_OFF);
  sim_kernel<<<1, 256, 0, stream>>>(qstb, tkb, out + SIM_OFF);

  // ---- decode chunk (split-K, M=128) ----
  build_xcat<<<768, 256, 0, stream>>>(cinp, emb, ctxb, xcatb);
  gemm_part<<<dim3(16,8,4), 256, 0, stream>>>(xcatb, Wci, ppart, DD+FF, 4, 128);
  gemm_combine<<<512, 256, 0, stream>>>(ppart, bci, cpos, hid1b, 4, 128, 0);
  gemm_part<<<dim3(16,8,4), 256, 0, stream>>>(hid1b, Wm1, ppart, FF, 4, 128);
  gemm_combine<<<512, 256, 0, stream>>>(ppart, bm1, nullptr, h2b, 4, 128, 1);
  gemm_part<<<dim3(16,8,4), 256, 0, stream>>>(h2b, Wm2, ppart, FF, 4, 128);
  gemm_combine<<<512, 256, 0, stream>>>(ppart, bm2, nullptr, hidb, 4, 128, 0);

  // ---- logits via MFMA ----
  split_h<<<512, 256, 0, stream>>>(hidb, hhb, hlb);
  logits_mfma<<<(VV+63)/64, 256, 0, stream>>>(hhb, hlb, Wlm, blm, out + LOGITS_OFF);

  // ---- losses ----
  softmax_nll<<<BB*CC, 512, 0, stream>>>(out + LOGITS_OFF, ctgt, tlb);
  loss_reduce<<<1, 128, 0, stream>>>(tlb, out + LOSS_OFF);
}

// Round 16
// 1610.048 us; speedup vs baseline: 1.0168x; 1.0168x over previous
//
#include <hip/hip_runtime.h>
#include <math.h>

// ---- problem dims ----
constexpr int BB = 16;      // batch
constexpr int SS = 1024;    // prefix len
constexpr int CC = 8;       // chunk len
constexpr int VV = 50257;   // vocab
constexpr int DD = 512;     // d_model
constexpr int EE = 8;       // experts
constexpr int HH = 512;     // expert hidden
constexpr int RR = 32;      // low rank
constexpr int FF = 1024;    // fused dim
constexpr int RTd = 512;    // target dim
constexpr int CDd = 64;     // code dim
constexpr int QQ = 128;     // query dim
constexpr int SCH = 128;    // s-chunk for AUG+scan

typedef short bf16x8 __attribute__((ext_vector_type(8)));
typedef float f32x4 __attribute__((ext_vector_type(4)));

__device__ __forceinline__ float sigm(float x){ return 1.0f/(1.0f+expf(-x)); }

__device__ __forceinline__ unsigned short f2bf(float f){
  unsigned int u = __float_as_uint(f);
  u += 0x7fff + ((u>>16)&1);
  return (unsigned short)(u>>16);
}
__device__ __forceinline__ float bf2f(unsigned short h){
  return __uint_as_float(((unsigned int)h)<<16);
}

// async global->LDS, 16B per lane; lds ptr wave-uniform, HW adds lane*16
__device__ __forceinline__ void gload16(unsigned short* l, const unsigned short* g){
  __builtin_amdgcn_global_load_lds(
      (const __attribute__((address_space(1))) unsigned int*)(g),
      (__attribute__((address_space(3))) unsigned int*)(l), 16, 0, 0);
}

// ---------------- gather_pack: emb[toks] -> packed bf16 hi/lo staging image ----------------
// xp layout: [b][c(8)][kc(16)][pb(1024)][8 shorts]; pb = row*8 + ((kq*2+h)^(row&7))
__global__ __launch_bounds__(256) void gather_pack(const int* __restrict__ toks,
    const float* __restrict__ emb, unsigned short* __restrict__ xp){
  int id = blockIdx.x*256 + threadIdx.x;        // 2,097,152 blocks
  int b = id >> 17;
  int rem = id & 131071;
  int c = rem >> 14;
  int rem2 = rem & 16383;
  int kc = rem2 >> 10;
  int pb = rem2 & 1023;
  int row = pb >> 3, q = pb & 7;
  int v = q ^ (row & 7);
  int kq = v >> 1, h = v & 1;
  int tok = toks[b*SS + c*128 + row];
  const float* src = emb + (size_t)tok*DD + kc*32 + kq*8;
  unsigned short o[8];
  #pragma unroll
  for (int j=0;j<8;j++){
    float f = src[j];
    unsigned short hi = f2bf(f);
    o[j] = h ? f2bf(f - bf2f(hi)) : hi;
  }
  ushort4* dst = (ushort4*)(xp + (size_t)id*8);
  dst[0] = make_ushort4(o[0],o[1],o[2],o[3]);
  dst[1] = make_ushort4(o[4],o[5],o[6],o[7]);
}

// ---------------- K2: summary = mean_s emb[toks] ----------------
__global__ __launch_bounds__(512) void colsum_part(const int* __restrict__ toks,
    const float* __restrict__ emb, float* __restrict__ part){
  int b = blockIdx.y, j = blockIdx.x, d = threadIdx.x;
  float s = 0.f;
  for (int k=0;k<64;k++){
    int tok = toks[b*SS + j*64 + k];
    s += emb[(size_t)tok*DD + d];
  }
  part[(b*16 + j)*DD + d] = s;
}
__global__ __launch_bounds__(512) void colsum_final(const float* __restrict__ part,
                                                    float* __restrict__ summary){
  int b = blockIdx.x, d = threadIdx.x;
  float s = 0.f;
  for (int j=0;j<16;j++) s += part[(b*16 + j)*DD + d];
  summary[b*DD + d] = s * (1.0f/1024.0f);
}

// ---------------- K3: gate MLP ----------------
__global__ __launch_bounds__(128) void gate_h1(const float* __restrict__ summary,
                                               const float* __restrict__ Wg1,
                                               const float* __restrict__ bg1,
                                               float* __restrict__ h1){
  int t = threadIdx.x; int j = blockIdx.x*128 + t;
  __shared__ float sm[16*512];
  for (int idx=t; idx<8192; idx+=128) sm[idx] = summary[idx];
  __syncthreads();
  float acc[16] = {0};
  for (int d=0; d<DD; d++){
    float w = Wg1[d*DD + j];
    #pragma unroll
    for (int b2=0;b2<16;b2++) acc[b2] += sm[b2*DD + d]*w;
  }
  #pragma unroll
  for (int b2=0;b2<16;b2++){ float v = acc[b2] + bg1[j]; h1[b2*DD + j] = v*sigm(v); }
}
__global__ __launch_bounds__(128) void gate_probs_k(const float* __restrict__ h1,
                                                    const float* __restrict__ Wg2,
                                                    const float* __restrict__ bg2,
                                                    float* __restrict__ gate){
  int t = threadIdx.x;         // 128 = 16 b x 8 e
  int b = t>>3, e = t&7;
  float acc = bg2[e];
  for (int d=0; d<DD; d++) acc += h1[b*DD + d]*Wg2[d*EE + e];
  __shared__ float lg[16][8];
  lg[b][e] = acc;
  __syncthreads();
  if (e==0){
    float m = -3.4e38f;
    for (int i=0;i<8;i++) m = fmaxf(m, lg[b][i]);
    float s = 0.f; float ex[8];
    for (int i=0;i<8;i++){ ex[i] = expf(lg[b][i]-m); s += ex[i]; }
    for (int i=0;i<8;i++) gate[b*EE + i] = ex[i]/s;
  }
}

// ---------------- W packers: f32 [e][k][c] -> staging images ----------------
// WPackAU: per (ec = e*8+ctile, kc): 1024 blocks [a(Ah,Al,Uh,Ul)][kq(4)][c(64)][8k]
__global__ __launch_bounds__(256) void convT_pack_au(const float* __restrict__ Wa,
    const float* __restrict__ Wu, unsigned short* __restrict__ WPackAU){
  const int ec = blockIdx.x;      // 64
  const int kc = blockIdx.y;      // 16
  const int e = ec >> 3, ct = ec & 7;
  __shared__ float ta[32][64];
  __shared__ float tu[32][64];
  const int t = threadIdx.x;
  for (int i=0;i<8;i++){
    int id = t + i*256;           // 2048
    int c = id & 63, kk = id >> 6;
    size_t src = ((size_t)e*DD + kc*32 + kk)*HH + ct*64 + c;
    ta[kk][c] = Wa[src];
    tu[kk][c] = Wu[src];
  }
  __syncthreads();
  unsigned short* o = WPackAU + ((size_t)ec*16 + kc)*8192;
  for (int i=0;i<8;i++){
    int idx4 = t + i*256;         // 2048 ushort4 units
    int blk = idx4 >> 1, half = idx4 & 1;
    int a = blk >> 8, kq = (blk >> 6) & 3, c = blk & 63;
    const float* src = (a >> 1) ? &tu[0][0] : &ta[0][0];
    unsigned short s4[4];
    #pragma unroll
    for (int j2=0;j2<4;j2++){
      int j = half*4 + j2;
      float f = src[(kq*8 + j)*64 + c];
      unsigned short hi = f2bf(f);
      s4[j2] = (a & 1) ? f2bf(f - bf2f(hi)) : hi;
    }
    *(ushort4*)&o[(size_t)idx4*4] = make_ushort4(s4[0],s4[1],s4[2],s4[3]);
  }
}
// WPackG: per (gt, kc): 512 blocks [a(hi,lo)][kq(4)][c(64)][8k]; gcol = gt*64+c -> (ee,r)
__global__ __launch_bounds__(256) void convT_pack_g(const float* __restrict__ Wge,
    unsigned short* __restrict__ WPackG){
  const int gt = blockIdx.x;      // 4
  const int kc = blockIdx.y;      // 16
  __shared__ float tg[32][64];
  const int t = threadIdx.x;
  for (int i=0;i<8;i++){
    int id = t + i*256;
    int c = id & 63, kk = id >> 6;
    int gcol = gt*64 + c;
    tg[kk][c] = Wge[((size_t)(gcol>>5)*DD + kc*32 + kk)*RR + (gcol & 31)];
  }
  __syncthreads();
  unsigned short* o = WPackG + ((size_t)gt*16 + kc)*4096;
  for (int i=0;i<4;i++){
    int idx4 = t + i*256;         // 1024 ushort4 units
    int blk = idx4 >> 1, half = idx4 & 1;
    int a = blk >> 8, kq = (blk >> 6) & 3, c = blk & 63;
    unsigned short s4[4];
    #pragma unroll
    for (int j2=0;j2<4;j2++){
      int j = half*4 + j2;
      float f = tg[kq*8 + j][c];
      unsigned short hi = f2bf(f);
      s4[j2] = a ? f2bf(f - bf2f(hi)) : hi;
    }
    *(ushort4*)&o[(size_t)idx4*4] = make_ushort4(s4[0],s4[1],s4[2],s4[3]);
  }
}

// ---------------- fused AUG(c) + scan(c-1), 2-phase dbuf staging ----------------
// blocks 0..127: scan (e,b). blocks 128..1215: aug: aid=bid-128, b=aid&15, ct=aid>>4.
//   ct<64: A+U tile (e=ct>>3, ctile=ct&7); ct 64..67: G tile
__global__ __launch_bounds__(512, 2) void aug_scan(
    const unsigned short* __restrict__ xp,
    const unsigned short* __restrict__ WPackAU, const unsigned short* __restrict__ WPackG,
    const float* __restrict__ ba, const float* __restrict__ bu, const float* __restrict__ bge,
    float* __restrict__ Aw, float* __restrict__ Uw, float* __restrict__ Gw,
    const float* __restrict__ Ar, const float* __restrict__ Ur, const float* __restrict__ Gr,
    const float* __restrict__ v_mat, const float* __restrict__ u_mat,
    float* __restrict__ states,
    int s0, int do_aug, int do_scan)
{
  __shared__ __align__(16) unsigned short lds[32768];   // 64 KB: 2 bufs x (16KB X + 16KB W)
  const int t = threadIdx.x;

  if (blockIdx.x < 128){
    // ================= scan path =================
    if (!do_scan) return;
    const int e = blockIdx.x >> 4;
    const int b = blockIdx.x & 15;
    const int r = t & 31, grp = t >> 5;     // 32 r x 16 groups
    float* stf   = (float*)lds;             // [2][512]
    float* partf = (float*)lds + 1024;      // [32][9]
    float* lowf  = (float*)lds + 1312;      // [32]
    float vreg[32];
    #pragma unroll
    for (int i=0;i<32;i++) vreg[i] = v_mat[((size_t)e*HH + grp*32 + i)*RR + r];
    float ureg[32];
    {
      const float4* up = (const float4*)(u_mat + ((size_t)e*HH + t)*RR);
      #pragma unroll
      for (int j=0;j<8;j++){
        float4 v4 = up[j];
        ureg[j*4+0]=v4.x; ureg[j*4+1]=v4.y; ureg[j*4+2]=v4.z; ureg[j*4+3]=v4.w;
      }
    }
    const size_t base  = ((size_t)e*BB + b)*HH + t;
    const size_t gbase = ((size_t)e*BB + b)*RR + r;
    const size_t strAU = (size_t)EE*BB*HH;
    const size_t strG  = (size_t)EE*BB*RR;
    float streg = states[base];
    stf[t] = streg;
    float a0 = Ar[base], u0 = Ur[base];
    float g0 = (t < 32) ? Gr[gbase] : 0.f;
    float a1 = Ar[base + strAU], u1 = Ur[base + strAU];
    float g1 = (t < 32) ? Gr[gbase + strG] : 0.f;
    __syncthreads();
    int cur = 0;
    for (int s=0; s<SCH; s++){
      float a2 = 0.f, u2 = 0.f, g2 = 0.f;
      if (s+2 < SCH){
        a2 = Ar[base + (size_t)(s+2)*strAU];
        u2 = Ur[base + (size_t)(s+2)*strAU];
        if (t < 32) g2 = Gr[gbase + (size_t)(s+2)*strG];
      }
      float p = 0.f;
      #pragma unroll
      for (int i=0;i<32;i++) p += stf[cur*512 + grp*32+i]*vreg[i];
      p += __shfl_xor(p, 32, 64);
      if ((t & 32) == 0) partf[r*9 + (grp>>1)] = p;
      __syncthreads();
      if (t < 32){
        float ss2 = 0.f;
        #pragma unroll
        for (int j=0;j<8;j++) ss2 += partf[t*9 + j];
        lowf[t] = ss2 * g0;
      }
      __syncthreads();
      float acc2 = 0.f;
      #pragma unroll
      for (int i=0;i<32;i++) acc2 += lowf[i]*ureg[i];
      streg = a0*streg + u0 + acc2;
      stf[(cur^1)*512 + t] = streg;
      cur ^= 1;
      a0=a1; u0=u1; g0=g1; a1=a2; u1=u2; g1=g2;
      __syncthreads();
    }
    states[base] = streg;
    return;
  }

  // ================= aug path =================
  if (!do_aug) return;
  const int aid = blockIdx.x - 128;
  const int b  = aid & 15;
  const int ct = aid >> 4;          // 0..67
  const int lane = t & 63, wv = t >> 6;
  const int cix = s0 >> 7;
  const unsigned short* xpc = xp + (((size_t)(b*8 + cix)) << 17);
  const int wo = wv*64;

  f32x4 acc[2][4] = {};
  const int cl15 = lane & 15;

  if (ct < 64){
    // ---- A+U tile: waves 0-3 = A strips, 4-7 = U strips ----
    const int e = ct >> 3;
    const int c0 = (ct & 7)*64;
    const unsigned short* wpc = WPackAU + (((size_t)ct) << 17);
    const int strip = wv & 3;
    const int mode  = wv >> 2;
    const int kq4 = lane >> 4;
    const int rr0 = strip*32 + cl15, rr1 = rr0 + 16;
    const int qh = (kq4*2) ^ (rr0 & 7);
    const int ql = (kq4*2+1) ^ (rr0 & 7);
    const int ab = mode*512;

#define STAGE_AU(BUF, KC) { \
    unsigned short* XB_ = lds + (BUF)*16384; \
    unsigned short* WB_ = XB_ + 8192; \
    const unsigned short* gx = xpc + (KC)*8192; \
    const unsigned short* gw = wpc + (KC)*8192; \
    gload16(XB_ + wo*8,        gx + (size_t)(wo + lane)*8); \
    gload16(XB_ + (512+wo)*8,  gx + (size_t)(512 + wo + lane)*8); \
    gload16(WB_ + wo*8,        gw + (size_t)(wo + lane)*8); \
    gload16(WB_ + (512+wo)*8,  gw + (size_t)(512 + wo + lane)*8); }

    STAGE_AU(0, 0)
    asm volatile("s_waitcnt vmcnt(0)" ::: "memory");
    __builtin_amdgcn_s_barrier();
    __builtin_amdgcn_sched_barrier(0);
    int cur = 0;
    for (int kc=0; kc<16; kc++){
      if (kc < 15) STAGE_AU(cur^1, kc+1)
      const unsigned short* XB = lds + cur*16384;
      const unsigned short* WB = XB + 8192;
      bf16x8 ah0 = *(const bf16x8*)&XB[(rr0*8 + qh)*8];
      bf16x8 al0 = *(const bf16x8*)&XB[(rr0*8 + ql)*8];
      bf16x8 ah1 = *(const bf16x8*)&XB[(rr1*8 + qh)*8];
      bf16x8 al1 = *(const bf16x8*)&XB[(rr1*8 + ql)*8];
      #pragma unroll
      for (int cf=0; cf<4; cf++){
        const int cc = cf*16 + cl15;
        bf16x8 bh = *(const bf16x8*)&WB[(ab + kq4*64 + cc)*8];
        bf16x8 bl = *(const bf16x8*)&WB[(ab + 256 + kq4*64 + cc)*8];
        acc[0][cf] = __builtin_amdgcn_mfma_f32_16x16x32_bf16(ah0, bh, acc[0][cf], 0,0,0);
        acc[0][cf] = __builtin_amdgcn_mfma_f32_16x16x32_bf16(ah0, bl, acc[0][cf], 0,0,0);
        acc[0][cf] = __builtin_amdgcn_mfma_f32_16x16x32_bf16(al0, bh, acc[0][cf], 0,0,0);
        acc[1][cf] = __builtin_amdgcn_mfma_f32_16x16x32_bf16(ah1, bh, acc[1][cf], 0,0,0);
        acc[1][cf] = __builtin_amdgcn_mfma_f32_16x16x32_bf16(ah1, bl, acc[1][cf], 0,0,0);
        acc[1][cf] = __builtin_amdgcn_mfma_f32_16x16x32_bf16(al1, bh, acc[1][cf], 0,0,0);
      }
      __builtin_amdgcn_sched_barrier(0);
      asm volatile("s_waitcnt vmcnt(0)" ::: "memory");
      __builtin_amdgcn_s_barrier();
      __builtin_amdgcn_sched_barrier(0);
      cur ^= 1;
    }
#undef STAGE_AU
    // epilogue: C/D col=lane&15, row=(lane>>4)*4+reg
    const int r4 = (lane >> 4) * 4;
    #pragma unroll
    for (int rf=0; rf<2; rf++){
      #pragma unroll
      for (int cf=0; cf<4; cf++){
        #pragma unroll
        for (int i=0;i<4;i++){
          int sl = strip*32 + rf*16 + r4 + i;
          int ce = c0 + cf*16 + cl15;
          float v = acc[rf][cf][i];
          if (mode == 0){
            v += ba[e*HH + ce];
            v = sigm(v);
            Aw[((size_t)(sl*EE + e)*BB + b)*HH + ce] = v;
          } else {
            v += bu[e*HH + ce];
            Uw[((size_t)(sl*EE + e)*BB + b)*HH + ce] = v;
          }
        }
      }
    }
  } else {
    // ---- G tile: 8 waves x 16 rows ----
    const int gt = ct - 64;
    const int c0 = gt*64;
    const unsigned short* wpc = WPackG + (((size_t)gt) << 16);
    const int kq4 = lane >> 4;
    const int rr0 = wv*16 + cl15;
    const int qh = (kq4*2) ^ (rr0 & 7);
    const int ql = (kq4*2+1) ^ (rr0 & 7);

#define STAGE_G(BUF, KC) { \
    unsigned short* XB_ = lds + (BUF)*16384; \
    unsigned short* WB_ = XB_ + 8192; \
    const unsigned short* gx = xpc + (KC)*8192; \
    const unsigned short* gw = wpc + (KC)*4096; \
    gload16(XB_ + wo*8,        gx + (size_t)(wo + lane)*8); \
    gload16(XB_ + (512+wo)*8,  gx + (size_t)(512 + wo + lane)*8); \
    gload16(WB_ + wo*8,        gw + (size_t)(wo + lane)*8); }

    STAGE_G(0, 0)
    asm volatile("s_waitcnt vmcnt(0)" ::: "memory");
    __builtin_amdgcn_s_barrier();
    __builtin_amdgcn_sched_barrier(0);
    int cur = 0;
    for (int kc=0; kc<16; kc++){
      if (kc < 15) STAGE_G(cur^1, kc+1)
      const unsigned short* XB = lds + cur*16384;
      const unsigned short* WB = XB + 8192;
      bf16x8 ah0 = *(const bf16x8*)&XB[(rr0*8 + qh)*8];
      bf16x8 al0 = *(const bf16x8*)&XB[(rr0*8 + ql)*8];
      #pragma unroll
      for (int cf=0; cf<4; cf++){
        const int cc = cf*16 + cl15;
        bf16x8 bh = *(const bf16x8*)&WB[(kq4*64 + cc)*8];
        bf16x8 bl = *(const bf16x8*)&WB[(256 + kq4*64 + cc)*8];
        acc[0][cf] = __builtin_amdgcn_mfma_f32_16x16x32_bf16(ah0, bh, acc[0][cf], 0,0,0);
        acc[0][cf] = __builtin_amdgcn_mfma_f32_16x16x32_bf16(ah0, bl, acc[0][cf], 0,0,0);
        acc[0][cf] = __builtin_amdgcn_mfma_f32_16x16x32_bf16(al0, bh, acc[0][cf], 0,0,0);
      }
      __builtin_amdgcn_sched_barrier(0);
      asm volatile("s_waitcnt vmcnt(0)" ::: "memory");
      __builtin_amdgcn_s_barrier();
      __builtin_amdgcn_sched_barrier(0);
      cur ^= 1;
    }
#undef STAGE_G
    const int r4 = (lane >> 4) * 4;
    #pragma unroll
    for (int cf=0; cf<4; cf++){
      #pragma unroll
      for (int i=0;i<4;i++){
        int sl = wv*16 + r4 + i;
        int g = c0 + cf*16 + cl15;
        int ee = g >> 5, r2 = g & 31;
        float v = acc[0][cf][i] + bge[ee*RR + r2];
        Gw[((size_t)(sl*EE + ee)*BB + b)*RR + r2] = v;
      }
    }
  }
}

// ---------------- K5: proj + gate-weighted fuse ----------------
__global__ __launch_bounds__(128) void proj_partial(const float* __restrict__ states,
    const float* __restrict__ Wp, const float* __restrict__ gate, float* __restrict__ pf){
  int fc = blockIdx.x, e = blockIdx.y, t = threadIdx.x;
  __shared__ float stl[16*512];
  for (int idx=t; idx<8192; idx+=128) stl[idx] = states[(size_t)e*8192 + idx];
  __syncthreads();
  int f = fc*128 + t;
  float acc[16] = {0};
  for (int h=0; h<HH; h++){
    float w = Wp[((size_t)e*HH + h)*FF + f];
    #pragma unroll
    for (int b2=0;b2<16;b2++) acc[b2] += stl[b2*HH + h]*w;
  }
  #pragma unroll
  for (int b2=0;b2<16;b2++) pf[((size_t)(e*16 + b2))*FF + f] = gate[b2*EE + e]*acc[b2];
}
__global__ __launch_bounds__(256) void fuse_reduce(const float* __restrict__ pf,
    const float* __restrict__ gate, const float* __restrict__ bp, float* __restrict__ fused){
  int idx = blockIdx.x*256 + threadIdx.x;     // 16*1024
  int b = idx >> 10, f = idx & 1023;
  float s = 0.f;
  #pragma unroll
  for (int e=0;e<8;e++) s += pf[((size_t)(e*16 + b))*FF + f] + gate[b*EE + e]*bp[e*FF + f];
  fused[idx] = s;
}

// ---------------- fq_linear: out = fake_quantize(in @ W + bias) ----------------
__global__ __launch_bounds__(128) void fq_linear(const float* __restrict__ in, int Kin,
    const float* __restrict__ W, const float* __restrict__ bias, float* __restrict__ out){
  int b = blockIdx.x, t = threadIdx.x;
  __shared__ float xin[1024];
  __shared__ float red[2];
  for (int k=t;k<Kin;k+=128) xin[k] = in[(size_t)b*Kin + k];
  __syncthreads();
  float acc = bias[t];
  for (int k=0;k<Kin;k++) acc += xin[k]*W[k*QQ + t];
  float ss = acc*acc;
  #pragma unroll
  for (int off=32; off; off>>=1) ss += __shfl_xor(ss, off, 64);
  if ((t&63)==0) red[t>>6] = ss;
  __syncthreads();
  float n = fmaxf(sqrtf(red[0]+red[1]), 1e-6f);
  float xn = acc / n;
  float q = fminf(fmaxf(rintf(xn*127.0f), -127.0f), 127.0f) * (1.0f/127.0f);
  out[b*QQ + t] = q;
}

// ---------------- K7: chunk/next embedding means -> t_in ----------------
__global__ __launch_bounds__(512) void chunk_means(const int* __restrict__ ct,
    const int* __restrict__ nct, const float* __restrict__ emb, float* __restrict__ tin){
  int b = blockIdx.x, d = threadIdx.x;
  float ce=0.f, ne=0.f;
  for (int c=0;c<CC;c++){
    ce += emb[(size_t)ct[b*CC+c]*DD + d];
    ne += emb[(size_t)nct[b*CC+c]*DD + d];
  }
  tin[b*1024 + d] = ce*0.125f;
  tin[b*1024 + 512 + d] = ne*0.125f;
}

// ---------------- K8: target_state ----------------
__global__ __launch_bounds__(512) void target_state_kernel(const float* __restrict__ tin,
    const float* __restrict__ Wt1, const float* __restrict__ bt1,
    const float* __restrict__ Wt2, const float* __restrict__ bt2, float* __restrict__ outts){
  int b = blockIdx.x, t = threadIdx.x;   // 512
  __shared__ float xin[1024];
  __shared__ float h1[512];
  __shared__ float red[8];
  for (int k=t;k<1024;k+=512) xin[k] = tin[b*1024 + k];
  __syncthreads();
  float acc = bt1[t];
  for (int k=0;k<1024;k++) acc += xin[k]*Wt1[k*RTd + t];
  acc = acc*sigm(acc);
  h1[t] = acc;
  __syncthreads();
  float y = bt2[t];
  for (int k=0;k<512;k++) y += h1[k]*Wt2[k*RTd + t];
  float ss = y*y;
  #pragma unroll
  for (int off=32; off; off>>=1) ss += __shfl_xor(ss, off, 64);
  if ((t&63)==0) red[t>>6] = ss;
  __syncthreads();
  float tot = 0.f;
  #pragma unroll
  for (int i=0;i<8;i++) tot += red[i];
  float n = fmaxf(sqrtf(tot), 1e-6f);
  outts[b*RTd + t] = y/n;
}

// ---------------- K11: write_state = normalize((ctx@Wwc+bwc)@Web) ----------------
__global__ __launch_bounds__(512) void write_state_kernel(const float* __restrict__ ctx,
    const float* __restrict__ Wwc, const float* __restrict__ bwc,
    const float* __restrict__ Web, float* __restrict__ wsn){
  int b = blockIdx.x, t = threadIdx.x;   // 512
  __shared__ float cx[1024];
  __shared__ float wc[64];
  __shared__ float red[8];
  for (int k=t;k<1024;k+=512) cx[k] = ctx[b*FF + k];
  __syncthreads();
  if (t < 64){
    float a = bwc[t];
    for (int k=0;k<1024;k++) a += cx[k]*Wwc[k*CDd + t];
    wc[t] = a;
  }
  __syncthreads();
  float y = 0.f;
  for (int k=0;k<64;k++) y += wc[k]*Web[k*RTd + t];
  float ss = y*y;
  #pragma unroll
  for (int off=32; off; off>>=1) ss += __shfl_xor(ss, off, 64);
  if ((t&63)==0) red[t>>6] = ss;
  __syncthreads();
  float tot = 0.f;
  #pragma unroll
  for (int i=0;i<8;i++) tot += red[i];
  float n = fmaxf(sqrtf(tot), 1e-6f);
  wsn[b*RTd + t] = y/n;
}

// ---------------- K12: sim ----------------
__global__ __launch_bounds__(256) void sim_kernel(const float* __restrict__ q,
    const float* __restrict__ k, float* __restrict__ out){
  int t = threadIdx.x;
  int i = t>>4, j = t&15;
  float s = 0.f;
  for (int c=0;c<QQ;c++) s += q[i*QQ + c]*k[j*QQ + c];
  out[t] = s / sqrtf(128.0f);
}

// ---------------- K13pre: xcat = [emb[chunk_inputs], ctx] ----------------
__global__ __launch_bounds__(256) void build_xcat(const int* __restrict__ ci,
    const float* __restrict__ emb, const float* __restrict__ ctx, float* __restrict__ xcat){
  int idx = blockIdx.x*256 + threadIdx.x;   // 128*1536
  int row = idx / 1536, k = idx % 1536;
  float v = (k < DD) ? emb[(size_t)ci[row]*DD + k] : ctx[(row>>3)*FF + (k - DD)];
  xcat[idx] = v;
}

// ---------------- split-K partial GEMM (N=1024 outputs) ----------------
__global__ __launch_bounds__(256) void gemm_part(const float* __restrict__ X,
    const float* __restrict__ W, float* __restrict__ part,
    int K, int KS, int M){
  const int t = threadIdx.x;
  const int col = blockIdx.x*64 + (t & 63);
  const int r0 = blockIdx.y*16;
  const int ks = blockIdx.z;
  const int rg = t >> 6;           // 4 groups x 4 rows
  const int kslice = K / KS;
  const int kbeg = ks*kslice;
  __shared__ float xs[16][65];
  float acc[4] = {};
  for (int k0=kbeg; k0<kbeg+kslice; k0+=64){
    #pragma unroll
    for (int i=0;i<4;i++){
      int id = t + i*256;
      int row = id >> 6, kk = id & 63;
      xs[row][kk] = X[(size_t)(r0+row)*K + k0 + kk];
    }
    __syncthreads();
    #pragma unroll 8
    for (int kk=0; kk<64; kk++){
      float w = W[(size_t)(k0+kk)*FF + col];
      #pragma unroll
      for (int i=0;i<4;i++) acc[i] += xs[rg*4+i][kk]*w;
    }
    __syncthreads();
  }
  #pragma unroll
  for (int i=0;i<4;i++)
    part[((size_t)ks*M + r0 + rg*4 + i)*FF + col] = acc[i];
}
__global__ __launch_bounds__(256) void gemm_combine(const float* __restrict__ part,
    const float* __restrict__ bias, const float* __restrict__ pos,
    float* __restrict__ outp, int KS, int M, int act){
  int idx = blockIdx.x*256 + threadIdx.x;     // M*1024
  int row = idx >> 10, col = idx & 1023;
  float v = bias[col];
  for (int k=0;k<KS;k++) v += part[(size_t)k*M*FF + idx];
  if (pos) v += pos[(row & 7)*FF + col];
  if (act) v = v*sigm(v);
  outp[idx] = v;
}

// ---------------- split hidden for logits ----------------
__global__ __launch_bounds__(256) void split_h(const float* __restrict__ hsrc,
    unsigned short* __restrict__ hh, unsigned short* __restrict__ hl){
  int idx = blockIdx.x*256 + threadIdx.x;   // 131072
  float f = hsrc[idx];
  unsigned short h = f2bf(f);
  hh[idx] = h;
  hl[idx] = f2bf(f - bf2f(h));
}

// ---------------- K15: logits via split-bf16 MFMA ----------------
__global__ __launch_bounds__(256) void logits_mfma(
    const unsigned short* __restrict__ hh, const unsigned short* __restrict__ hl,
    const float* __restrict__ Wlm, const float* __restrict__ blm,
    float* __restrict__ out){
  const int t = threadIdx.x;
  const int lane = t & 63, w = t >> 6;
  const int cb = blockIdx.x * 64;
  __shared__ __align__(16) unsigned short xsh[8*128*8];   // block = row*8 + (kq^(row&7))
  __shared__ __align__(16) unsigned short xsl[8*128*8];
  __shared__ __align__(16) unsigned short wsh[8*64*8];    // block = kq*64 + cc (linear)
  __shared__ __align__(16) unsigned short wsl[8*64*8];
  f32x4 acc[2][4] = {};
  for (int kc=0; kc<16; kc++){
    const int k0 = kc*64;
    #pragma unroll
    for (int i=0;i<4;i++){
      int id = t + i*256;
      int kq = id & 7, row = id >> 3;
      int pb = row*8 + (kq ^ (row&7));
      *(uint4*)&xsh[pb*8] = *(const uint4*)(hh + (size_t)row*FF + k0 + kq*8);
      *(uint4*)&xsl[pb*8] = *(const uint4*)(hl + (size_t)row*FF + k0 + kq*8);
    }
    #pragma unroll
    for (int i=0;i<2;i++){
      int id = t + i*256;
      int cc = id & 63, kq = id >> 6;
      int c = cb + cc; if (c >= VV) c = VV - 1;
      unsigned short h8[8], l8[8];
      #pragma unroll
      for (int j=0;j<8;j++){
        float f = Wlm[(size_t)(k0 + kq*8 + j)*VV + c];
        unsigned short h = f2bf(f);
        h8[j] = h;
        l8[j] = f2bf(f - bf2f(h));
      }
      int pb = kq*64 + cc;
      *(ushort4*)&wsh[pb*8]   = make_ushort4(h8[0],h8[1],h8[2],h8[3]);
      *(ushort4*)&wsh[pb*8+4] = make_ushort4(h8[4],h8[5],h8[6],h8[7]);
      *(ushort4*)&wsl[pb*8]   = make_ushort4(l8[0],l8[1],l8[2],l8[3]);
      *(ushort4*)&wsl[pb*8+4] = make_ushort4(l8[4],l8[5],l8[6],l8[7]);
    }
    __syncthreads();
    #pragma unroll
    for (int ks=0; ks<2; ks++){
      const int kq4 = ks*4 + (lane>>4);
      const int rr0 = w*32 + (lane&15);
      const int rr1 = rr0 + 16;
      bf16x8 ah0 = *(const bf16x8*)&xsh[(rr0*8 + (kq4^(rr0&7)))*8];
      bf16x8 ah1 = *(const bf16x8*)&xsh[(rr1*8 + (kq4^(rr1&7)))*8];
      bf16x8 al0 = *(const bf16x8*)&xsl[(rr0*8 + (kq4^(rr0&7)))*8];
      bf16x8 al1 = *(const bf16x8*)&xsl[(rr1*8 + (kq4^(rr1&7)))*8];
      #pragma unroll
      for (int cf=0; cf<4; cf++){
        const int cc = cf*16 + (lane&15);
        bf16x8 bh = *(const bf16x8*)&wsh[(kq4*64 + cc)*8];
        bf16x8 bl = *(const bf16x8*)&wsl[(kq4*64 + cc)*8];
        acc[0][cf] = __builtin_amdgcn_mfma_f32_16x16x32_bf16(ah0, bh, acc[0][cf], 0,0,0);
        acc[0][cf] = __builtin_amdgcn_mfma_f32_16x16x32_bf16(ah0, bl, acc[0][cf], 0,0,0);
        acc[0][cf] = __builtin_amdgcn_mfma_f32_16x16x32_bf16(al0, bh, acc[0][cf], 0,0,0);
        acc[1][cf] = __builtin_amdgcn_mfma_f32_16x16x32_bf16(ah1, bh, acc[1][cf], 0,0,0);
        acc[1][cf] = __builtin_amdgcn_mfma_f32_16x16x32_bf16(ah1, bl, acc[1][cf], 0,0,0);
        acc[1][cf] = __builtin_amdgcn_mfma_f32_16x16x32_bf16(al1, bh, acc[1][cf], 0,0,0);
      }
    }
    __syncthreads();
  }
  const int cl = lane & 15;
  const int r4 = (lane >> 4) * 4;
  #pragma unroll
  for (int rf=0; rf<2; rf++){
    #pragma unroll
    for (int cf=0; cf<4; cf++){
      int c = cb + cf*16 + cl;
      if (c >= VV) continue;
      float bb = blm[c];
      #pragma unroll
      for (int i=0;i<4;i++){
        int row = w*32 + rf*16 + r4 + i;
        out[(size_t)row*VV + c] = acc[rf][cf][i] + bb;
      }
    }
  }
}

// ---------------- K16: online per-row logsumexp + NLL ----------------
__global__ __launch_bounds__(512) void softmax_nll(const float* __restrict__ logits,
    const int* __restrict__ tgt, float* __restrict__ tl){
  const int row = blockIdx.x;
  const float* p = logits + (size_t)row*VV;
  const int t = threadIdx.x;
  float m = -3.4e38f, s = 0.f;
  for (int c=t; c<VV; c+=512){
    float v = p[c];
    if (v > m){ s = s*expf(m - v) + 1.0f; m = v; }
    else s += expf(v - m);
  }
  #pragma unroll
  for (int off=32; off; off>>=1){
    float m2 = __shfl_xor(m, off, 64);
    float s2 = __shfl_xor(s, off, 64);
    float mn = fmaxf(m, m2);
    s = s*expf(m - mn) + s2*expf(m2 - mn);
    m = mn;
  }
  __shared__ float ms[8], ssh[8];
  if ((t&63)==0){ ms[t>>6] = m; ssh[t>>6] = s; }
  __syncthreads();
  if (t==0){
    float M = ms[0], S = ssh[0];
    for (int i=1;i<8;i++){
      float mn = fmaxf(M, ms[i]);
      S = S*expf(M-mn) + ssh[i]*expf(ms[i]-mn);
      M = mn;
    }
    tl[row] = M + logf(S) - p[tgt[row]];
  }
}
__global__ __launch_bounds__(128) void loss_reduce(const float* __restrict__ tl,
                                                   float* __restrict__ out){
  int t = threadIdx.x;
  float v = tl[t];
  #pragma unroll
  for (int off=32; off; off>>=1) v += __shfl_xor(v, off, 64);
  __shared__ float r2[2];
  if ((t&63)==0) r2[t>>6] = v;
  __syncthreads();
  if (t==0) out[0] = (r2[0]+r2[1]) * (1.0f/128.0f);
}

// =======================================================================
extern "C" void kernel_launch(void* const* d_in, const int* in_sizes, int n_in,
                              void* d_out, int out_size, void* d_ws, size_t ws_size,
                              hipStream_t stream){
  (void)in_sizes; (void)n_in; (void)out_size;
  const int*  prefix = (const int*)d_in[0];
  const int*  cinp   = (const int*)d_in[1];
  const int*  ctgt   = (const int*)d_in[2];
  const int*  nctk   = (const int*)d_in[3];
  const float* emb  = (const float*)d_in[4];
  const float* Wa   = (const float*)d_in[5];
  const float* ba   = (const float*)d_in[6];
  const float* Wge  = (const float*)d_in[7];
  const float* bge  = (const float*)d_in[8];
  const float* Wu   = (const float*)d_in[9];
  const float* bu   = (const float*)d_in[10];
  const float* u_mat= (const float*)d_in[11];
  const float* v_mat= (const float*)d_in[12];
  const float* Wp   = (const float*)d_in[13];
  const float* bp   = (const float*)d_in[14];
  const float* Wg1  = (const float*)d_in[15];
  const float* bg1  = (const float*)d_in[16];
  const float* Wg2  = (const float*)d_in[17];
  const float* bg2  = (const float*)d_in[18];
  const float* Wq   = (const float*)d_in[19];
  const float* bq   = (const float*)d_in[20];
  const float* Wt1  = (const float*)d_in[21];
  const float* bt1  = (const float*)d_in[22];
  const float* Wt2  = (const float*)d_in[23];
  const float* bt2  = (const float*)d_in[24];
  const float* Wk   = (const float*)d_in[25];
  const float* bk   = (const float*)d_in[26];
  const float* Web  = (const float*)d_in[27];
  const float* Wwc  = (const float*)d_in[28];
  const float* bwc  = (const float*)d_in[29];
  const float* Wc1  = (const float*)d_in[30];
  const float* bc1  = (const float*)d_in[31];
  const float* Wc2  = (const float*)d_in[32];
  const float* bc2  = (const float*)d_in[33];
  const float* cpos = (const float*)d_in[34];
  const float* Wci  = (const float*)d_in[35];
  const float* bci  = (const float*)d_in[36];
  const float* Wm1  = (const float*)d_in[37];
  const float* bm1  = (const float*)d_in[38];
  const float* Wm2  = (const float*)d_in[39];
  const float* bm2  = (const float*)d_in[40];
  const float* Wlm  = (const float*)d_in[41];
  const float* blm  = (const float*)d_in[42];

  float* ws = (float*)d_ws;
  size_t off = 0;
  unsigned short* xp = (unsigned short*)(ws + off); off += (size_t)BB*SS*DD;   // hi+lo packed, 33.5 MB
  float* Abuf0  = ws + off; off += (size_t)SCH*EE*BB*HH;
  float* Ubuf0  = ws + off; off += (size_t)SCH*EE*BB*HH;
  float* Gbuf0  = ws + off; off += (size_t)SCH*EE*BB*RR;
  float* statesb= ws + off; off += (size_t)EE*BB*HH;
  float* partb  = ws + off; off += (size_t)BB*16*DD;
  float* summb  = ws + off; off += (size_t)BB*DD;
  float* h1b    = ws + off; off += (size_t)BB*DD;
  float* gateb  = ws + off; off += (size_t)BB*EE;
  float* pfb    = ws + off; off += (size_t)EE*BB*FF;
  float* fusedb = ws + off; off += (size_t)BB*FF;
  float* qstb   = ws + off; off += (size_t)BB*QQ;
  float* tinb   = ws + off; off += (size_t)BB*2*DD;
  float* tstb   = ws + off; off += (size_t)BB*RTd;
  float* tkb    = ws + off; off += (size_t)BB*QQ;
  float* ctxb   = ws + off; off += (size_t)BB*FF;
  float* hctxb  = ws + off; off += (size_t)BB*FF;
  float* wsnb   = ws + off; off += (size_t)BB*RTd;
  float* xcatb  = ws + off; off += (size_t)BB*CC*(DD+FF);
  float* hid1b  = ws + off; off += (size_t)BB*CC*FF;
  float* h2b    = ws + off; off += (size_t)BB*CC*FF;
  float* hidb   = ws + off; off += (size_t)BB*CC*FF;
  float* tlb    = ws + off; off += (size_t)BB*CC;
  float* ppart  = ws + off; off += (size_t)4*BB*CC*FF;
  unsigned short* WPackAU = (unsigned short*)(ws + off); off += (size_t)EE*DD*HH*2;  // 16.7 MB
  unsigned short* WPackG  = (unsigned short*)(ws + off); off += (size_t)EE*DD*RR;
  unsigned short* hhb  = (unsigned short*)(ws + off); off += (size_t)BB*CC*FF/2;
  unsigned short* hlb  = (unsigned short*)(ws + off); off += (size_t)BB*CC*FF/2;
  // double-buffer extension (fused schedule only)
  float* Abuf1  = ws + off; off += (size_t)SCH*EE*BB*HH;
  float* Ubuf1  = ws + off; off += (size_t)SCH*EE*BB*HH;
  float* Gbuf1  = ws + off; off += (size_t)SCH*EE*BB*RR;
  const bool fused = ws_size >= off * sizeof(float);

  float* out = (float*)d_out;
  const size_t LOGITS_OFF = 0;
  const size_t LOSS_OFF = (size_t)BB*CC*VV;
  const size_t SIM_OFF  = LOSS_OFF + 1;
  const size_t WK_OFF   = SIM_OFF + (size_t)BB*BB;

  // ---- one-time weight packs (bf16 hi/lo, staging-image layout) ----
  convT_pack_au<<<dim3(64,16), 256, 0, stream>>>(Wa, Wu, WPackAU);
  convT_pack_g<<<dim3(4,16), 256, 0, stream>>>(Wge, WPackG);

  // ---- prefix encode ----
  gather_pack<<<8192, 256, 0, stream>>>(prefix, emb, xp);
  colsum_part<<<dim3(16,16), 512, 0, stream>>>(prefix, emb, partb);
  colsum_final<<<16, 512, 0, stream>>>(partb, summb);
  gate_h1<<<4, 128, 0, stream>>>(summb, Wg1, bg1, h1b);
  gate_probs_k<<<1, 128, 0, stream>>>(h1b, Wg2, bg2, gateb);

  hipMemsetAsync(statesb, 0, (size_t)EE*BB*HH*sizeof(float), stream);

  if (fused){
    for (int c=0; c<=8; c++){
      int da = (c<8) ? 1 : 0;
      int dscn = (c>=1) ? 1 : 0;
      float* Aw = (c&1) ? Abuf1 : Abuf0;
      float* Uw = (c&1) ? Ubuf1 : Ubuf0;
      float* Gw = (c&1) ? Gbuf1 : Gbuf0;
      const float* Ar = ((c-1)&1) ? Abuf1 : Abuf0;
      const float* Ur = ((c-1)&1) ? Ubuf1 : Ubuf0;
      const float* Gr = ((c-1)&1) ? Gbuf1 : Gbuf0;
      int grid = da ? 1216 : 128;
      aug_scan<<<grid, 512, 0, stream>>>(xp, WPackAU, WPackG, ba, bu, bge,
          Aw, Uw, Gw, Ar, Ur, Gr, v_mat, u_mat, statesb,
          c*SCH, da, dscn);
    }
  } else {
    for (int c=0; c<8; c++){
      aug_scan<<<1216, 512, 0, stream>>>(xp, WPackAU, WPackG, ba, bu, bge,
          Abuf0, Ubuf0, Gbuf0, Abuf0, Ubuf0, Gbuf0, v_mat, u_mat, statesb,
          c*SCH, 1, 0);
      aug_scan<<<128, 512, 0, stream>>>(xp, WPackAU, WPackG, ba, bu, bge,
          Abuf0, Ubuf0, Gbuf0, Abuf0, Ubuf0, Gbuf0, v_mat, u_mat, statesb,
          c*SCH, 0, 1);
    }
  }

  proj_partial<<<dim3(8,8), 128, 0, stream>>>(statesb, Wp, gateb, pfb);
  fuse_reduce<<<64, 256, 0, stream>>>(pfb, gateb, bp, fusedb);

  // ---- query / target / key ----
  fq_linear<<<16, 128, 0, stream>>>(fusedb, FF, Wq, bq, qstb);
  chunk_means<<<16, 512, 0, stream>>>(ctgt, nctk, emb, tinb);
  target_state_kernel<<<16, 512, 0, stream>>>(tinb, Wt1, bt1, Wt2, bt2, tstb);
  fq_linear<<<16, 128, 0, stream>>>(tstb, RTd, Wk, bk, tkb);

  // ---- read_context (split-K, M=16) ----
  gemm_part<<<dim3(16,1,4), 256, 0, stream>>>(fusedb, Wc1, ppart, FF, 4, 16);
  gemm_combine<<<64, 256, 0, stream>>>(ppart, bc1, nullptr, hctxb, 4, 16, 1);
  gemm_part<<<dim3(16,1,4), 256, 0, stream>>>(hctxb, Wc2, ppart, FF, 4, 16);
  gemm_combine<<<64, 256, 0, stream>>>(ppart, bc2, nullptr, ctxb, 4, 16, 0);

  // ---- write path ----
  write_state_kernel<<<16, 512, 0, stream>>>(ctxb, Wwc, bwc, Web, wsnb);
  fq_linear<<<16, 128, 0, stream>>>(wsnb, RTd, Wk, bk, out + WK_OFF);
  sim_kernel<<<1, 256, 0, stream>>>(qstb, tkb, out + SIM_OFF);

  // ---- decode chunk (split-K, M=128) ----
  build_xcat<<<768, 256, 0, stream>>>(cinp, emb, ctxb, xcatb);
  gemm_part<<<dim3(16,8,4), 256, 0, stream>>>(xcatb, Wci, ppart, DD+FF, 4, 128);
  gemm_combine<<<512, 256, 0, stream>>>(ppart, bci, cpos, hid1b, 4, 128, 0);
  gemm_part<<<dim3(16,8,4), 256, 0, stream>>>(hid1b, Wm1, ppart, FF, 4, 128);
  gemm_combine<<<512, 256, 0, stream>>>(ppart, bm1, nullptr, h2b, 4, 128, 1);
  gemm_part<<<dim3(16,8,4), 256, 0, stream>>>(h2b, Wm2, ppart, FF, 4, 128);
  gemm_combine<<<512, 256, 0, stream>>>(ppart, bm2, nullptr, hidb, 4, 128, 0);

  // ---- logits via MFMA ----
  split_h<<<512, 256, 0, stream>>>(hidb, hhb, hlb);
  logits_mfma<<<(VV+63)/64, 256, 0, stream>>>(hhb, hlb, Wlm, blm, out + LOGITS_OFF);

  // ---- losses ----
  softmax_nll<<<BB*CC, 512, 0, stream>>>(out + LOGITS_OFF, ctgt, tlb);
  loss_reduce<<<1, 128, 0, stream>>>(tlb, out + LOSS_OFF);
}